// Round 2
// baseline (147.967 us; speedup 1.0000x reference)
//
#include <hip/hip_runtime.h>

// Problem constants (fixed shapes from setup_inputs)
constexpr int NB = 8;     // batch
constexpr int ND = 1024;  // d = 32*32 cells
constexpr int NHS = 32;   // hs
constexpr int NWS = 32;   // ws
constexpr int NS = 500;   // noise samples n
constexpr int NK = 16;    // k
constexpr int NC = 3;     // channels
constexpr int NH = 1024;  // H
constexpr int NW = 1024;  // W
constexpr int SH = 32;    // H/hs
constexpr int SW = 32;    // W/ws
constexpr int NP = 64;    // patch size
constexpr int PTOP = 16;  // (p - sh)/2
constexpr int PLEFT = 16; // (p - sw)/2
constexpr float SIGMA = 0.05f;

// ---------------- Phase 1: per-batch min-max normalize ----------------
__global__ void normalize_kernel(const float* __restrict__ scores,
                                 float* __restrict__ s_norm) {
    int b = blockIdx.x;
    int t = threadIdx.x;
    float v[4];
    float mn, mx;
#pragma unroll
    for (int q = 0; q < 4; q++) v[q] = scores[b * ND + t + 256 * q];
    mn = fminf(fminf(v[0], v[1]), fminf(v[2], v[3]));
    mx = fmaxf(fmaxf(v[0], v[1]), fmaxf(v[2], v[3]));
#pragma unroll
    for (int off = 1; off < 64; off <<= 1) {
        mn = fminf(mn, __shfl_xor(mn, off));
        mx = fmaxf(mx, __shfl_xor(mx, off));
    }
    __shared__ float smn[4], smx[4];
    int wave = t >> 6, lane = t & 63;
    if (lane == 0) { smn[wave] = mn; smx[wave] = mx; }
    __syncthreads();
    mn = fminf(fminf(smn[0], smn[1]), fminf(smn[2], smn[3]));
    mx = fmaxf(fmaxf(smx[0], smx[1]), fmaxf(smx[2], smx[3]));
    float den = mx - mn + 1e-5f;
#pragma unroll
    for (int q = 0; q < 4; q++)
        s_norm[b * ND + t + 256 * q] = (v[q] - mn) / den;
}

// ---------------- Phase 2: per-sample top-16 -> integer histogram ----------------
// One block (256 threads) per (b, sample). Perturbed row in registers, 4/thread.
// 16 iterations of block argmax (tie -> lowest index, matches lax.top_k),
// then rank-by-index (== sorted idx position) and integer atomicAdd.
__global__ void topk_kernel(const float* __restrict__ s_norm,
                            const float* __restrict__ noise,
                            int* __restrict__ counts) {
    int blk = blockIdx.x;
    int b = blk / NS;
    int smp = blk - b * NS;
    int t = threadIdx.x;

    const float* sp = s_norm + b * ND;
    const float* npp = noise + (size_t)(b * NS + smp) * ND;

    float v[4];
#pragma unroll
    for (int q = 0; q < 4; q++) {
        int j = t + 256 * q;
        v[q] = sp[j] + npp[j] * SIGMA;
    }

    __shared__ float wv[4];
    __shared__ int wj[4];
    __shared__ int sel[NK];
    __shared__ int winner;

    for (int it = 0; it < NK; it++) {
        // thread-local argmax over its 4 elems (ascending j => strict > keeps lowest idx)
        float bv = v[0];
        int bj = t;
#pragma unroll
        for (int q = 1; q < 4; q++) {
            if (v[q] > bv) { bv = v[q]; bj = t + 256 * q; }
        }
        // wave butterfly reduce (64 lanes), tie -> lower index
#pragma unroll
        for (int off = 1; off < 64; off <<= 1) {
            float ov = __shfl_xor(bv, off);
            int oj = __shfl_xor(bj, off);
            if (ov > bv || (ov == bv && oj < bj)) { bv = ov; bj = oj; }
        }
        int wave = t >> 6, lane = t & 63;
        if (lane == 0) { wv[wave] = bv; wj[wave] = bj; }
        __syncthreads();
        if (t == 0) {
            float fv = wv[0];
            int fj = wj[0];
#pragma unroll
            for (int w = 1; w < 4; w++) {
                if (wv[w] > fv || (wv[w] == fv && wj[w] < fj)) { fv = wv[w]; fj = wj[w]; }
            }
            sel[it] = fj;
            winner = fj;
        }
        __syncthreads();
        int fj = winner;
        if ((fj & 255) == t) v[fj >> 8] = -1e30f;
        // no extra barrier needed: next write to winner is after the next __syncthreads()
    }
    __syncthreads();
    if (t < NK) {
        int myj = sel[t];
        int rank = 0;
#pragma unroll
        for (int u = 0; u < NK; u++) rank += (sel[u] < myj) ? 1 : 0;
        atomicAdd(&counts[(b * NK + rank) * ND + myj], 1);
    }
}

// ---------------- Phase 3: sparse weighted patch gather ----------------
// Block per (b, kk, c, yhalf). Counts row staged in LDS; loop cells, skip zeros.
// Thread t: x = t&63, yq = t>>6; covers y = half*32 + yq + 4*r, r in [0,8).
__global__ void gather_kernel(const int* __restrict__ counts,
                              const float* __restrict__ x_high,
                              float* __restrict__ out) {
    int blk = blockIdx.x;            // b*96 + kk*6 + c*2 + half
    int b = blk / (NK * NC * 2);
    int rem = blk % (NK * NC * 2);
    int kk = rem / (NC * 2);
    int rem2 = rem % (NC * 2);
    int c = rem2 / 2;
    int half = rem2 & 1;
    int t = threadIdx.x;

    __shared__ int cnt[ND];
#pragma unroll
    for (int q = 0; q < 4; q++)
        cnt[t + 256 * q] = counts[(b * NK + kk) * ND + t + 256 * q];
    __syncthreads();

    const float* xp = x_high + (size_t)(b * NC + c) * NH * NW;
    int x = t & 63;
    int yq = t >> 6;  // 0..3
    int ybase = half * 32 + yq;

    float acc[8];
#pragma unroll
    for (int r = 0; r < 8; r++) acc[r] = 0.f;

    const float invn = 1.0f / (float)NS;
    for (int cell = 0; cell < ND; cell++) {
        int cc = cnt[cell];
        if (cc == 0) continue;
        float w = (float)cc * invn;
        int i = cell >> 5;
        int j = cell & 31;
        int col = j * SW + x - PLEFT;
        bool colok = (unsigned)col < (unsigned)NW;
        int rowbase = i * SH + ybase - PTOP;
#pragma unroll
        for (int r = 0; r < 8; r++) {
            int row = rowbase + 4 * r;
            float xv = 0.f;
            if (colok && (unsigned)row < (unsigned)NH)
                xv = xp[(size_t)row * NW + col];
            acc[r] += w * xv;
        }
    }

    float* op = out + ((size_t)(b * NK + kk) * NC + c) * NP * NP;
#pragma unroll
    for (int r = 0; r < 8; r++) {
        int y = ybase + 4 * r;
        op[y * NP + x] = acc[r];
    }
}

extern "C" void kernel_launch(void* const* d_in, const int* in_sizes, int n_in,
                              void* d_out, int out_size, void* d_ws, size_t ws_size,
                              hipStream_t stream) {
    const float* scores = (const float*)d_in[0];
    const float* x_high = (const float*)d_in[1];
    const float* noise  = (const float*)d_in[2];

    float* s_norm = (float*)d_ws;
    int* counts = (int*)((char*)d_ws + NB * ND * sizeof(float));

    hipMemsetAsync(counts, 0, (size_t)NB * NK * ND * sizeof(int), stream);
    normalize_kernel<<<NB, 256, 0, stream>>>(scores, s_norm);
    topk_kernel<<<NB * NS, 256, 0, stream>>>(s_norm, noise, counts);
    gather_kernel<<<NB * NK * NC * 2, 256, 0, stream>>>(counts, x_high, (float*)d_out);
}

// Round 3
// 59.712 us; speedup vs baseline: 2.4780x; 2.4780x over previous
//
#include <hip/hip_runtime.h>

// Problem constants (fixed shapes from setup_inputs)
constexpr int NB = 8;     // batch
constexpr int ND = 1024;  // d = 32*32 cells
constexpr int NS = 500;   // noise samples n
constexpr int NK = 16;    // k
constexpr int NC = 3;     // channels
constexpr int NH = 1024;  // H
constexpr int NW = 1024;  // W
constexpr int SH = 32;    // H/hs
constexpr int SW = 32;    // W/ws
constexpr int NP = 64;    // patch size
constexpr int PTOP = 16;  // (p - sh)/2
constexpr int PLEFT = 16; // (p - sw)/2
constexpr float SIGMA = 0.05f;

// ---------------- Phase 1: per-batch min-max normalize ----------------
__global__ void normalize_kernel(const float* __restrict__ scores,
                                 float* __restrict__ s_norm) {
    int b = blockIdx.x;
    int t = threadIdx.x;
    float v[4];
    float mn, mx;
#pragma unroll
    for (int q = 0; q < 4; q++) v[q] = scores[b * ND + t + 256 * q];
    mn = fminf(fminf(v[0], v[1]), fminf(v[2], v[3]));
    mx = fmaxf(fmaxf(v[0], v[1]), fmaxf(v[2], v[3]));
#pragma unroll
    for (int off = 1; off < 64; off <<= 1) {
        mn = fminf(mn, __shfl_xor(mn, off));
        mx = fmaxf(mx, __shfl_xor(mx, off));
    }
    __shared__ float smn[4], smx[4];
    int wave = t >> 6, lane = t & 63;
    if (lane == 0) { smn[wave] = mn; smx[wave] = mx; }
    __syncthreads();
    mn = fminf(fminf(smn[0], smn[1]), fminf(smn[2], smn[3]));
    mx = fmaxf(fmaxf(smx[0], smx[1]), fmaxf(smx[2], smx[3]));
    float den = mx - mn + 1e-5f;
#pragma unroll
    for (int q = 0; q < 4; q++)
        s_norm[b * ND + t + 256 * q] = (v[q] - mn) / den;
}

// ---------------- Phase 2: wave-per-sample top-16 -> integer histogram ----------------
// One 64-lane wave per (b, sample): 16 elems/lane in registers (j = q*64+lane,
// coalesced), 16 iterations of {local argmax, butterfly reduce with index
// tie-break (lowest index wins, matching lax.top_k)}, statically-indexed
// masking, then rank-by-index via shfl and one integer atomicAdd per winner.
__global__ void topk_kernel(const float* __restrict__ s_norm,
                            const float* __restrict__ noise,
                            int* __restrict__ counts) {
    int t = threadIdx.x;
    int wave = t >> 6, lane = t & 63;
    int sid = blockIdx.x * 4 + wave;          // 0 .. NB*NS-1 (grid is exact)
    int b = sid / NS;

    const float* sp = s_norm + b * ND;
    const float* npp = noise + (size_t)sid * ND;   // sid == b*NS + smp

    float v[16];
#pragma unroll
    for (int q = 0; q < 16; q++) {
        int j = q * 64 + lane;
        v[q] = sp[j] + npp[j] * SIGMA;
    }

    int myj = 0x7fffffff;
    for (int it = 0; it < NK; it++) {
        // local argmax over the 16 register elems; j increases with q, so
        // strict > keeps the lowest index on ties
        float bv = v[0];
        int bq = 0;
#pragma unroll
        for (int q = 1; q < 16; q++)
            if (v[q] > bv) { bv = v[q]; bq = q; }
        int bj = bq * 64 + lane;
        // 64-lane butterfly, tie -> lower global index
#pragma unroll
        for (int off = 1; off < 64; off <<= 1) {
            float ov = __shfl_xor(bv, off);
            int oj = __shfl_xor(bj, off);
            if (ov > bv || (ov == bv && oj < bj)) { bv = ov; bj = oj; }
        }
        // every lane now holds the winner (bv, bj)
        if (lane == it) myj = bj;
        int wq = bj >> 6, wl = bj & 63;
        // static indexing (runtime-indexed reg arrays spill to scratch)
#pragma unroll
        for (int q = 0; q < 16; q++)
            v[q] = (q == wq && lane == wl) ? -1e30f : v[q];
    }

    // rank of each selected index within the selected set (== sorted position)
    int rank = 0;
#pragma unroll
    for (int u = 0; u < NK; u++) {
        int other = __shfl(myj, u);
        rank += (other < myj) ? 1 : 0;
    }
    if (lane < NK)
        atomicAdd(&counts[(b * NK + rank) * ND + myj], 1);
}

// ---------------- Phase 2.5: compact nonzero cells (deterministic) ----------------
// Block per (b,kk). Thread t owns cells [4t, 4t+4). Block-ordered prefix scan
// -> packed entries (cell<<16 | count) in ascending cell order.
__global__ void compact_kernel(const int* __restrict__ counts,
                               int* __restrict__ lists,
                               int* __restrict__ ncells) {
    int bk = blockIdx.x;   // 0..127
    int t = threadIdx.x;
    int lane = t & 63, wave = t >> 6;
    const int* cp = counts + bk * ND;

    int c4[4];
    int flags = 0, cnt = 0;
#pragma unroll
    for (int q = 0; q < 4; q++) {
        c4[q] = cp[t * 4 + q];
        if (c4[q] != 0) { flags |= 1 << q; cnt++; }
    }
    // wave inclusive scan of cnt
    int incl = cnt;
#pragma unroll
    for (int off = 1; off < 64; off <<= 1) {
        int o = __shfl_up(incl, off);
        if (lane >= off) incl += o;
    }
    int excl = incl - cnt;
    __shared__ int wtot[4];
    if (lane == 63) wtot[wave] = incl;
    __syncthreads();
    int base = 0;
    for (int w = 0; w < wave; w++) base += wtot[w];
    int pos = base + excl;
    int* lp = lists + bk * NS;
#pragma unroll
    for (int q = 0; q < 4; q++) {
        if (flags & (1 << q)) {
            lp[pos++] = ((t * 4 + q) << 16) | c4[q];
        }
    }
    if (t == 0)
        ncells[bk] = wtot[0] + wtot[1] + wtot[2] + wtot[3];
}

// ---------------- Phase 3: sparse weighted patch gather ----------------
// Block per (b, kk, c, y-eighth): 3072 blocks -> 8+ blocks/CU resident.
// Compact list staged in LDS (broadcast reads). Thread: x = t&63, rows
// y = g*8 + (t>>6) and +4. Guarded coalesced loads (256B/wave/row).
__global__ void gather_kernel(const int* __restrict__ lists,
                              const int* __restrict__ ncells,
                              const float* __restrict__ x_high,
                              float* __restrict__ out) {
    int blk = blockIdx.x;            // bk*24 + c*8 + g
    int g = blk & 7;
    int c = (blk >> 3) % NC;
    int bk = blk / (NC * 8);         // b*16 + kk
    int t = threadIdx.x;

    int n = ncells[bk];
    __shared__ int lst[NS];
    for (int i = t; i < n; i += 256) lst[i] = lists[bk * NS + i];
    __syncthreads();

    const float* xp = x_high + (size_t)((bk >> 4) * NC + c) * NH * NW;
    int x = t & 63;
    int yq = t >> 6;                 // 0..3
    int y0 = g * 8 + yq;             // covers y0 and y0+4

    float a0 = 0.f, a1 = 0.f;
    const float invn = 1.0f / (float)NS;
    for (int e = 0; e < n; e++) {
        int pk = lst[e];
        int cell = pk >> 16;
        float w = (float)(pk & 0xffff) * invn;
        int i = cell >> 5;
        int j = cell & 31;
        int col = j * SW + x - PLEFT;
        bool colok = (unsigned)col < (unsigned)NW;
        int row0 = i * SH + y0 - PTOP;
        int row1 = row0 + 4;
        float v0 = (colok && (unsigned)row0 < (unsigned)NH)
                       ? xp[(size_t)row0 * NW + col] : 0.f;
        float v1 = (colok && (unsigned)row1 < (unsigned)NH)
                       ? xp[(size_t)row1 * NW + col] : 0.f;
        a0 += w * v0;
        a1 += w * v1;
    }

    float* op = out + (size_t)(bk * NC + c) * NP * NP;
    op[(g * 8 + yq) * NP + x] = a0;
    op[(g * 8 + yq + 4) * NP + x] = a1;
}

extern "C" void kernel_launch(void* const* d_in, const int* in_sizes, int n_in,
                              void* d_out, int out_size, void* d_ws, size_t ws_size,
                              hipStream_t stream) {
    const float* scores = (const float*)d_in[0];
    const float* x_high = (const float*)d_in[1];
    const float* noise  = (const float*)d_in[2];

    char* ws = (char*)d_ws;
    float* s_norm = (float*)ws;                              // 8*1024 f32   = 32 KB
    int* counts   = (int*)(ws + 32 * 1024);                  // 128*1024 int = 512 KB
    int* lists    = (int*)(ws + 32 * 1024 + 512 * 1024);     // 128*500 int  = 250 KB
    int* ncells   = (int*)(ws + 32 * 1024 + 512 * 1024 + 256 * 1024);  // 128 int

    hipMemsetAsync(counts, 0, (size_t)NB * NK * ND * sizeof(int), stream);
    normalize_kernel<<<NB, 256, 0, stream>>>(scores, s_norm);
    topk_kernel<<<NB * NS / 4, 256, 0, stream>>>(s_norm, noise, counts);
    compact_kernel<<<NB * NK, 256, 0, stream>>>(counts, lists, ncells);
    gather_kernel<<<NB * NK * NC * 8, 256, 0, stream>>>(lists, ncells, x_high, (float*)d_out);
}